// Round 18
// baseline (235.376 us; speedup 1.0000x reference)
//
#include <hip/hip_runtime.h>
#include <stdint.h>

typedef unsigned long long ull;

#define BATCH 16
#define NA 9
#define HH 128
#define WW 128
#define HW (HH*WW)            // 16384
#define NITEMS (NA*HW)        // 147456 per batch
#define PRE 6000
#define POST 300
#define NMS_T 0.7f
#define NBINS 4096            // top-12 bits of sortable key
#define NSLICE 16             // histogram slices per batch
#define CAP 8192
#define CBLK 144              // compact blocks per batch (1024 items each)
#define S1CH 2048             // per-block chunk for sort stage 1
#define NCH ((PRE + 63) / 64) // 94 NMS candidate chunks (64-wide)
#define CNTSTRIDE 32          // one 128B line per batch counter (atomic contention fix)

__device__ __forceinline__ uint32_t fkey(float f) {
    uint32_t u = __float_as_uint(f);
    return u ^ ((u & 0x80000000u) ? 0xFFFFFFFFu : 0x80000000u);
}

__device__ __forceinline__ ull shfl_xor_u64(ull x, int m) {
    uint32_t lo = (uint32_t)x, hi = (uint32_t)(x >> 32);
    lo = (uint32_t)__shfl_xor((int)lo, m, 64);
    hi = (uint32_t)__shfl_xor((int)hi, m, 64);
    return ((ull)hi << 32) | lo;
}

__device__ __forceinline__ ull ce_sel(ull a, ull b, bool takeMax) {
    return takeMax ? (a >= b ? a : b) : (a <= b ? a : b);
}

// K1: fused histogram + findbucket. Each (batch,slice) block builds a 4-way
// sub-histogram in LDS (cuts same-bin atomic serialization), writes its slice,
// then release-signals; the LAST block per batch merges slices and finds the
// threshold bucket (device-scope fences handle cross-XCD visibility, G16).
__global__ __launch_bounds__(1024) void k_histfb(const float4* __restrict__ scores4,
                                                 uint32_t* __restrict__ hist,
                                                 uint32_t* __restrict__ done,
                                                 uint32_t* __restrict__ bucket,
                                                 uint32_t* __restrict__ cnt) {
    int b = blockIdx.x / NSLICE;
    int sl = blockIdx.x % NSLICE;
    int t = threadIdx.x;
    int sub = (t >> 6) & 3;                       // wave % 4 sub-histogram
    __shared__ uint32_t lh[4][NBINS];             // 64 KB
    __shared__ uint32_t sprev;
    __shared__ uint32_t csum[256];
    __shared__ uint32_t csuf[257];
    for (int i = t; i < 4 * NBINS; i += 1024) ((uint32_t*)lh)[i] = 0;
    __syncthreads();
    size_t base4 = ((size_t)b * (2 * NA * HW) + (size_t)NA * HW) / 4;
    const int PER = NITEMS / NSLICE / 4;          // 2304 float4 per slice
    size_t s4 = base4 + (size_t)sl * PER;
    for (int v = t; v < PER; v += 1024) {
        float4 f = scores4[s4 + v];
        atomicAdd(&lh[sub][fkey(f.x) >> 20], 1u);
        atomicAdd(&lh[sub][fkey(f.y) >> 20], 1u);
        atomicAdd(&lh[sub][fkey(f.z) >> 20], 1u);
        atomicAdd(&lh[sub][fkey(f.w) >> 20], 1u);
    }
    __syncthreads();
    uint32_t* o = hist + ((size_t)b * NSLICE + sl) * NBINS;
    for (int i = t; i < NBINS; i += 1024)
        o[i] = lh[0][i] + lh[1][i] + lh[2][i] + lh[3][i];
    __threadfence();                              // release this thread's writes
    __syncthreads();                              // all threads' stores drained + fenced
    if (t == 0) sprev = atomicAdd(&done[b * CNTSTRIDE], 1u);
    __syncthreads();
    if (sprev != NSLICE - 1) return;              // uniform exit
    // last block for batch b
    __threadfence();                              // acquire: invalidate stale lines
    if (t == 0) cnt[b * CNTSTRIDE] = 0;           // zero compact counter
    const uint32_t* hb = hist + (size_t)b * NSLICE * NBINS;
    uint32_t binv[16];
    uint32_t s = 0;
    if (t < 256) {
        for (int u = 0; u < 16; ++u) {
            uint32_t v = 0;
            for (int slc = 0; slc < NSLICE; ++slc) v += hb[(size_t)slc * NBINS + t * 16 + u];
            binv[u] = v; s += v;
        }
        csum[t] = s;
    }
    __syncthreads();
    if (t == 0) {
        uint32_t acc = 0;
        csuf[256] = 0;
        for (int c = 255; c >= 0; --c) { acc += csum[c]; csuf[c] = acc; }
    }
    __syncthreads();
    if (t < 256) {
        uint32_t cum = csuf[t + 1];
        for (int u = 15; u >= 0; --u) {
            uint32_t c = binv[u];
            if (cum < PRE && cum + c >= PRE) bucket[b] = (uint32_t)(t * 16 + u);
            cum += c;
        }
    }
}

// decode + clip one proposal; store packed sort key and box at compact position.
__device__ __forceinline__ void decode_store(int rem, uint32_t key, uint32_t pos, int b,
                                             const float* __restrict__ deltas,
                                             const float* __restrict__ anchors,
                                             float limx, float limy,
                                             ull* __restrict__ pb, float4* __restrict__ bC) {
#pragma clang fp contract(off)
    int a = rem / HW;                 // anchor channel
    int pix = rem - a * HW;           // h*W + w
    uint32_t idx = (uint32_t)(pix * NA + a);
    // key desc, then ~idx desc (= idx asc); pos never decides ((key,idx) unique).
    pb[pos] = ((ull)key << 32) | ((ull)((~idx) & 0x3FFFFu) << 13) | pos;
    int wx = pix & (WW - 1);
    int hy = pix >> 7;
    const float* D = deltas + (size_t)b * (4 * NA * HW) + (size_t)(4 * a) * HW + hy * WW + wx;
    float dx = D[0], dy = D[HW], dw = D[2 * HW], dh = D[3 * HW];
    float ax1 = anchors[4 * a + 0], ay1 = anchors[4 * a + 1];
    float ax2 = anchors[4 * a + 2], ay2 = anchors[4 * a + 3];
    float sx = (float)(wx * 16), sy = (float)(hy * 16);
    float x1 = ax1 + sx, y1 = ay1 + sy, x2 = ax2 + sx, y2 = ay2 + sy;
    float w = x2 - x1 + 1.0f;
    float h = y2 - y1 + 1.0f;
    float cx = x1 + 0.5f * w;
    float cy = y1 + 0.5f * h;
    float pcx = dx * w + cx;
    float pcy = dy * h + cy;
    float pw = (float)exp((double)dw) * w;
    float ph = (float)exp((double)dh) * h;
    float px1 = pcx - 0.5f * pw;
    float py1 = pcy - 0.5f * ph;
    float px2 = pcx + 0.5f * pw;
    float py2 = pcy + 0.5f * ph;
    px1 = fminf(fmaxf(px1, 0.0f), limx);
    py1 = fminf(fmaxf(py1, 0.0f), limy);
    px2 = fminf(fmaxf(px2, 0.0f), limx);
    py2 = fminf(fmaxf(py2, 0.0f), limy);
    bC[pos] = make_float4(px1, py1, px2, py2);
}

// K3: compact + DECODE at full parallelism (2304 blocks); one padded-line atomic per block
__global__ __launch_bounds__(256) void k_compact(const float4* __restrict__ scores4,
                                                 const uint32_t* __restrict__ bucket,
                                                 uint32_t* __restrict__ cnt,
                                                 ull* __restrict__ pairs,
                                                 float4* __restrict__ boxesC,
                                                 const float* __restrict__ deltas,
                                                 const float* __restrict__ im_info,
                                                 const float* __restrict__ anchors) {
    int b = blockIdx.x / CBLK;
    int blk = blockIdx.x % CBLK;
    int t = threadIdx.x;
    int lane = t & 63, wid = t >> 6;
    uint32_t bkt = bucket[b];
    size_t base4 = ((size_t)b * (2 * NA * HW) + (size_t)NA * HW) / 4;
    float4 f = scores4[base4 + (size_t)blk * 256 + t];
    int item0 = blk * 1024 + t * 4;
    uint32_t k0 = fkey(f.x), k1 = fkey(f.y), k2 = fkey(f.z), k3 = fkey(f.w);
    bool p0 = (k0 >> 20) >= bkt, p1 = (k1 >> 20) >= bkt;
    bool p2 = (k2 >> 20) >= bkt, p3 = (k3 >> 20) >= bkt;
    ull m0 = __ballot(p0), m1 = __ballot(p1);
    ull m2 = __ballot(p2), m3 = __ballot(p3);
    uint32_t c0 = (uint32_t)__popcll(m0), c1 = (uint32_t)__popcll(m1);
    uint32_t c2 = (uint32_t)__popcll(m2), c3 = (uint32_t)__popcll(m3);
    uint32_t wcnt = c0 + c1 + c2 + c3;
    __shared__ uint32_t swc[4];
    __shared__ uint32_t sbase;
    if (lane == 0) swc[wid] = wcnt;
    __syncthreads();
    if (t == 0) {
        uint32_t a0 = swc[0], a1 = swc[1], a2 = swc[2], a3 = swc[3];
        uint32_t tot = a0 + a1 + a2 + a3;
        sbase = tot ? atomicAdd(&cnt[b * CNTSTRIDE], tot) : 0u;
        swc[0] = 0; swc[1] = a0; swc[2] = a0 + a1; swc[3] = a0 + a1 + a2;
    }
    __syncthreads();
    uint32_t wbase = sbase + swc[wid];
    ull below = ((ull)1 << lane) - 1ull;
    ull* pb = pairs + (size_t)b * CAP;
    float4* bC = boxesC + (size_t)b * CAP;
    float limx = im_info[b * 3 + 1] - 1.0f;
    float limy = im_info[b * 3 + 0] - 1.0f;
    uint32_t pos;
    if (p0) { pos = wbase + (uint32_t)__popcll(m0 & below);
              if (pos < CAP) decode_store(item0 + 0, k0, pos, b, deltas, anchors, limx, limy, pb, bC); }
    if (p1) { pos = wbase + c0 + (uint32_t)__popcll(m1 & below);
              if (pos < CAP) decode_store(item0 + 1, k1, pos, b, deltas, anchors, limx, limy, pb, bC); }
    if (p2) { pos = wbase + c0 + c1 + (uint32_t)__popcll(m2 & below);
              if (pos < CAP) decode_store(item0 + 2, k2, pos, b, deltas, anchors, limx, limy, pb, bC); }
    if (p3) { pos = wbase + c0 + c1 + c2 + (uint32_t)__popcll(m3 & below);
              if (pos < CAP) decode_store(item0 + 3, k3, pos, b, deltas, anchors, limx, limy, pb, bC); }
}

// K4: fused per-chunk bitonic sort (ALL chunks descending) + rank-merge.
// 4 blocks per batch sort their 2048-chunk and release-signal; the LAST block
// stages all 4 sorted chunks in LDS and computes final position = own index +
// 3 binary searches (exact on unique keys; pad zeros rank >= PRE), scattering
// pre-decoded boxes via the pos field.
__global__ __launch_bounds__(1024) void k_sortrank(ull* __restrict__ pairs,
                                                   const uint32_t* __restrict__ cnt,
                                                   uint32_t* __restrict__ done,
                                                   const float4* __restrict__ boxesC,
                                                   float4* __restrict__ boxes) {
    int b = blockIdx.x >> 2;
    int m = blockIdx.x & 3;
    int t = threadIdx.x;
    __shared__ ull lb[2][S1CH + (S1CH >> 3)];      // 36.9 KB
    __shared__ ull s[CAP];                         // 64 KB
    __shared__ uint32_t sprev;
    uint32_t n = cnt[b * CNTSTRIDE];
    if (n > CAP) n = CAP;
    ull* pb = pairs + (size_t)b * CAP;
    int base = m * S1CH;
    ull v[2];
#pragma unroll
    for (int r = 0; r < 2; ++r) {
        int e = base + 2 * t + r;
        v[r] = (e < (int)n) ? pb[e] : 0ull;
    }
    int phase = 0;
    for (int k = 2; k <= S1CH; k <<= 1) {
        bool topk = (k == S1CH);                   // final stage: descending everywhere
        for (int j = k >> 1; j > 0; j >>= 1) {
            if (j == 1) {
                int el = 2 * t;
                bool up = topk ? true : ((el & k) == 0);
                ull a = v[0], c = v[1];
                if ((a < c) == up) { v[0] = c; v[1] = a; }
            } else if (j <= 64) {
                int lm = j >> 1;
#pragma unroll
                for (int r = 0; r < 2; ++r) {
                    ull pv = shfl_xor_u64(v[r], lm);
                    int el = 2 * t + r;
                    bool up = topk ? true : ((el & k) == 0);
                    bool takeMax = (up == ((el & j) == 0));
                    v[r] = ce_sel(v[r], pv, takeMax);
                }
            } else {
                ull* buf = lb[phase & 1];
                ++phase;
#pragma unroll
                for (int r = 0; r < 2; ++r) { int el = 2 * t + r; buf[el + (el >> 3)] = v[r]; }
                __syncthreads();
#pragma unroll
                for (int r = 0; r < 2; ++r) {
                    int el = 2 * t + r;
                    int ep = el ^ j;
                    ull pv = buf[ep + (ep >> 3)];
                    bool up = topk ? true : ((el & k) == 0);
                    bool takeMax = (up == ((el & j) == 0));
                    v[r] = ce_sel(v[r], pv, takeMax);
                }
            }
        }
    }
#pragma unroll
    for (int r = 0; r < 2; ++r) pb[base + 2 * t + r] = v[r];
    __threadfence();                               // release sorted chunk
    __syncthreads();                               // all stores drained + fenced
    if (t == 0) sprev = atomicAdd(&done[b * CNTSTRIDE], 1u);
    __syncthreads();
    if (sprev != 3) return;                        // uniform exit
    // last block: rank-merge
    __threadfence();                               // acquire
    for (int e = t; e < CAP; e += 1024) s[e] = pb[e];
    __syncthreads();
    const float4* bC = boxesC + (size_t)b * CAP;
    float4* bo = boxes + (size_t)b * PRE;
#pragma unroll
    for (int r = 0; r < 8; ++r) {
        int e = (t << 3) + r;
        ull x = s[e];
        int mc = e >> 11;                          // own chunk
        uint32_t rank = (uint32_t)(e & 2047);
#pragma unroll
        for (int q = 0; q < 4; ++q) {
            if (q == mc) continue;
            const ull* cq = s + (q << 11);
            int lo = 0, hi = S1CH;                 // first idx with cq[idx] <= x
            while (lo < hi) {
                int mid = (lo + hi) >> 1;
                if (cq[mid] > x) lo = mid + 1; else hi = mid;
            }
            rank += (uint32_t)lo;
        }
        if (rank < PRE) bo[rank] = bC[(uint32_t)(x & 0x1FFFu)];
    }
}

// K5: precompute the 64x64 diagonal suppression matrices for ALL chunks in
// parallel (1504 blocks). Bit-identical IoU code.
__global__ __launch_bounds__(256) void k_diag(const float4* __restrict__ boxes,
                                              ull* __restrict__ smaskG) {
#pragma clang fp contract(off)
    int b = blockIdx.x / NCH;
    int ch = blockIdx.x % NCH;
    int lane = threadIdx.x & 63;
    int wv = threadIdx.x >> 6;             // 0..3
    int c0 = ch * 64;
    int c = c0 + lane;
    float4 cb = (c < PRE) ? boxes[(size_t)b * PRE + c] : make_float4(0.f, 0.f, 0.f, 0.f);
    float ca = (cb.z - cb.x + 1.0f) * (cb.w - cb.y + 1.0f);
    ull* mrow = smaskG + ((size_t)b * NCH + ch) * 64;
    for (int ii = 0; ii < 16; ++ii) {
        int i = wv * 16 + ii;
        int ci = c0 + i;
        float4 ib = (ci < PRE) ? boxes[(size_t)b * PRE + ci] : make_float4(0.f, 0.f, 0.f, 0.f);
        float ia = (ib.z - ib.x + 1.0f) * (ib.w - ib.y + 1.0f);
        float iwr = fminf(ib.z, cb.z) - fmaxf(ib.x, cb.x) + 1.0f;
        float ihr = fminf(ib.w, cb.w) - fmaxf(ib.y, cb.y) + 1.0f;
        bool sup = false;
        if (iwr > 0.0f && ihr > 0.0f) {    // exact: else iou == 0
            float inter = iwr * ihr;
            sup = (inter / ((ia + ca) - inter)) > NMS_T;
        }
        ull m = __ballot(sup);
        if (lane == 0) mrow[i] = m;
    }
}

// K6: 64-wide matrix-greedy NMS (round-15 structure). Per round: 16 waves test
// the 64 candidates vs kept list (slice 16, x4 independent-load unroll), wave 0
// preloads its mask row, B1, wave-0 PARALLEL-MIS greedy (exact lexicographic
// greedy, ~2-4 butterfly iterations), B2.
__global__ __launch_bounds__(1024) void k_nms(const float4* __restrict__ boxes,
                                              const ull* __restrict__ smaskG,
                                              float* __restrict__ out) {
#pragma clang fp contract(off)
    const int b = blockIdx.x;
    const int t = threadIdx.x;
    const int lane = t & 63;
    const int wv = t >> 6;                 // 0..15
    __shared__ float4 kbox[POST + 64];     // kept boxes, index order
    __shared__ float  karea[POST + 64];
    __shared__ ull    killm[16];
    __shared__ int    skept;
    if (t == 0) skept = 0;
    __syncthreads();
    const ull below = ((ull)1 << lane) - 1ull;
    for (int r = 0; r < NCH; ++r) {
        int kept = skept;                  // uniform (post-barrier)
        if (kept >= POST) break;
        int c0 = r * 64;
        int c = c0 + lane;
        bool valid = (c < PRE);
        float4 cb = valid ? boxes[(size_t)b * PRE + c]
                          : make_float4(0.f, 0.f, 0.f, 0.f);
        float ca = (cb.z - cb.x + 1.0f) * (cb.w - cb.y + 1.0f);
        ull rowmask = 0;
        if (wv == 0) rowmask = smaskG[((size_t)b * NCH + r) * 64 + lane];  // hidden under vs-kept
        // vs-kept: slice wv of 16, unrolled x4 with independent loads
        bool killed = false;
        for (int k = wv; k < kept; k += 64) {
            int k1 = k + 16, k2 = k + 32, k3 = k + 48;
            float4 b0 = kbox[k];
            float4 b1v, b2v, b3v;
            float a0 = karea[k], a1 = 0.f, a2 = 0.f, a3 = 0.f;
            bool h1 = k1 < kept, h2 = k2 < kept, h3 = k3 < kept;
            if (h1) { b1v = kbox[k1]; a1 = karea[k1]; }
            if (h2) { b2v = kbox[k2]; a2 = karea[k2]; }
            if (h3) { b3v = kbox[k3]; a3 = karea[k3]; }
            bool kk = false;
            {
                float iw = fminf(b0.z, cb.z) - fmaxf(b0.x, cb.x) + 1.0f;
                float ih = fminf(b0.w, cb.w) - fmaxf(b0.y, cb.y) + 1.0f;
                if (iw > 0.0f && ih > 0.0f) {
                    float inter = iw * ih;
                    kk |= (inter / ((a0 + ca) - inter)) > NMS_T;
                }
            }
            if (h1) {
                float iw = fminf(b1v.z, cb.z) - fmaxf(b1v.x, cb.x) + 1.0f;
                float ih = fminf(b1v.w, cb.w) - fmaxf(b1v.y, cb.y) + 1.0f;
                if (iw > 0.0f && ih > 0.0f) {
                    float inter = iw * ih;
                    kk |= (inter / ((a1 + ca) - inter)) > NMS_T;
                }
            }
            if (h2) {
                float iw = fminf(b2v.z, cb.z) - fmaxf(b2v.x, cb.x) + 1.0f;
                float ih = fminf(b2v.w, cb.w) - fmaxf(b2v.y, cb.y) + 1.0f;
                if (iw > 0.0f && ih > 0.0f) {
                    float inter = iw * ih;
                    kk |= (inter / ((a2 + ca) - inter)) > NMS_T;
                }
            }
            if (h3) {
                float iw = fminf(b3v.z, cb.z) - fmaxf(b3v.x, cb.x) + 1.0f;
                float ih = fminf(b3v.w, cb.w) - fmaxf(b3v.y, cb.y) + 1.0f;
                if (iw > 0.0f && ih > 0.0f) {
                    float inter = iw * ih;
                    kk |= (inter / ((a3 + ca) - inter)) > NMS_T;
                }
            }
            if (kk) { killed = true; break; }
        }
        ull km = __ballot(killed);         // unconditional -> no stale data
        if (lane == 0) killm[wv] = km;
        __syncthreads();                   // B1: kills visible
        if (wv == 0) {
            ull kill = 0;
#pragma unroll
            for (int q = 0; q < 16; ++q) kill |= killm[q];   // uniform LDS reads
            ull rem = __ballot(valid) & ~kill;
            ull rowm = rowmask & ~(1ull << lane);            // neighbors excl self
            ull keptm = 0;
            int total = kept;
            while (rem && total < POST) {  // parallel-MIS greedy (exact)
                bool alive = (rem >> lane) & 1ull;
                bool pick = alive && ((rowm & rem & below) == 0ull);
                ull pickm = __ballot(pick);
                ull contrib = pick ? rowm : 0ull;            // kept neighborhoods
                contrib |= shfl_xor_u64(contrib, 1);
                contrib |= shfl_xor_u64(contrib, 2);
                contrib |= shfl_xor_u64(contrib, 4);
                contrib |= shfl_xor_u64(contrib, 8);
                contrib |= shfl_xor_u64(contrib, 16);
                contrib |= shfl_xor_u64(contrib, 32);
                keptm |= pickm;
                total += (int)__popcll(pickm);
                rem &= ~(pickm | contrib);
            }
            int rank = (int)__popcll(keptm & below);
            if ((keptm >> lane) & 1ull) {
                kbox[kept + rank] = cb;
                karea[kept + rank] = ca;
            }
            if (lane == 0) skept = kept + (int)__popcll(keptm);
        }
        __syncthreads();                   // B2: kept list + count visible
    }
    int kf = skept < POST ? skept : POST;
    for (int k = t; k < POST; k += 1024) {
        float4 v = (k < kf) ? kbox[k] : make_float4(0.f, 0.f, 0.f, 0.f);
        float* o = out + ((size_t)b * POST + k) * 5;
        o[0] = (float)b;
        o[1] = v.x; o[2] = v.y; o[3] = v.z; o[4] = v.w;
    }
}

extern "C" void kernel_launch(void* const* d_in, const int* in_sizes, int n_in,
                              void* d_out, int out_size, void* d_ws, size_t ws_size,
                              hipStream_t stream) {
    const float* scores  = (const float*)d_in[0];
    const float* deltas  = (const float*)d_in[1];
    const float* im_info = (const float*)d_in[2];
    const float* anchors = (const float*)d_in[3];
    float* out = (float*)d_out;

    char* ws = (char*)d_ws;
    const size_t HIST_B  = (size_t)BATCH * NSLICE * NBINS * 4;   // 4 MiB
    const size_t CNT_B   = (size_t)BATCH * CNTSTRIDE * 4;        // 2 KiB (padded lines)
    const size_t BKT_B   = 64;
    const size_t DONE_B  = 2 * (size_t)BATCH * CNTSTRIDE * 4;    // 4 KiB (2 counter arrays)
    const size_t PAIRS_B = (size_t)BATCH * CAP * 8;              // 1 MiB
    const size_t BOXC_B  = (size_t)BATCH * CAP * 16;             // 2 MiB
    const size_t BOX_B   = (size_t)BATCH * PRE * 16;             // 1.5 MiB
    uint32_t* hist   = (uint32_t*)ws;
    uint32_t* cnt    = (uint32_t*)(ws + HIST_B);
    uint32_t* bkt    = (uint32_t*)(ws + HIST_B + CNT_B);
    uint32_t* doneH  = (uint32_t*)(ws + HIST_B + CNT_B + BKT_B);
    uint32_t* doneS  = doneH + BATCH * CNTSTRIDE;
    ull* pairs       = (ull*)(ws + HIST_B + CNT_B + BKT_B + DONE_B);
    float4* boxesC   = (float4*)(ws + HIST_B + CNT_B + BKT_B + DONE_B + PAIRS_B);
    float4* boxes    = (float4*)(ws + HIST_B + CNT_B + BKT_B + DONE_B + PAIRS_B + BOXC_B);
    ull* smaskG      = (ull*)(ws + HIST_B + CNT_B + BKT_B + DONE_B + PAIRS_B + BOXC_B + BOX_B);

    hipMemsetAsync(doneH, 0, DONE_B, stream);
    k_histfb<<<BATCH * NSLICE, 1024, 0, stream>>>((const float4*)scores, hist, doneH, bkt, cnt);
    k_compact<<<BATCH * CBLK, 256, 0, stream>>>((const float4*)scores, bkt, cnt, pairs,
                                                boxesC, deltas, im_info, anchors);
    k_sortrank<<<BATCH * 4, 1024, 0, stream>>>(pairs, cnt, doneS, boxesC, boxes);
    k_diag<<<BATCH * NCH, 256, 0, stream>>>(boxes, smaskG);
    k_nms<<<BATCH, 1024, 0, stream>>>(boxes, smaskG, out);
}

// Round 19
// 107.334 us; speedup vs baseline: 2.1929x; 2.1929x over previous
//
#include <hip/hip_runtime.h>
#include <stdint.h>

typedef unsigned long long ull;

#define BATCH 16
#define NA 9
#define HH 128
#define WW 128
#define HW (HH*WW)            // 16384
#define NITEMS (NA*HW)        // 147456 per batch
#define PRE 6000
#define POST 300
#define NMS_T 0.7f
#define NBINS 4096            // top-12 bits of sortable key
#define NSLICE 16             // histogram slices per batch
#define CAP 8192
#define CBLK 144              // compact blocks per batch (1024 items each)
#define S1CH 2048             // per-block chunk for sort stage 1
#define NCH ((PRE + 63) / 64) // 94 NMS candidate chunks (64-wide)
#define CNTSTRIDE 32          // one 128B line per batch counter (atomic contention fix)

__device__ __forceinline__ uint32_t fkey(float f) {
    uint32_t u = __float_as_uint(f);
    return u ^ ((u & 0x80000000u) ? 0xFFFFFFFFu : 0x80000000u);
}

__device__ __forceinline__ ull shfl_xor_u64(ull x, int m) {
    uint32_t lo = (uint32_t)x, hi = (uint32_t)(x >> 32);
    lo = (uint32_t)__shfl_xor((int)lo, m, 64);
    hi = (uint32_t)__shfl_xor((int)hi, m, 64);
    return ((ull)hi << 32) | lo;
}

__device__ __forceinline__ ull ce_sel(ull a, ull b, bool takeMax) {
    return takeMax ? (a >= b ? a : b) : (a <= b ? a : b);
}

// K1: per-(batch,slice) LDS histogram of top-12 key bits; non-atomic global write
__global__ __launch_bounds__(1024) void k_hist(const float4* __restrict__ scores4,
                                               uint32_t* __restrict__ hist) {
    int b = blockIdx.x / NSLICE;
    int sl = blockIdx.x % NSLICE;
    int t = threadIdx.x;
    __shared__ uint32_t lh[NBINS];
    for (int i = t; i < NBINS; i += 1024) lh[i] = 0;
    __syncthreads();
    size_t base4 = ((size_t)b * (2 * NA * HW) + (size_t)NA * HW) / 4;
    const int PER = NITEMS / NSLICE / 4;          // 2304 float4 per slice
    size_t s4 = base4 + (size_t)sl * PER;
    for (int v = t; v < PER; v += 1024) {
        float4 f = scores4[s4 + v];
        atomicAdd(&lh[fkey(f.x) >> 20], 1u);
        atomicAdd(&lh[fkey(f.y) >> 20], 1u);
        atomicAdd(&lh[fkey(f.z) >> 20], 1u);
        atomicAdd(&lh[fkey(f.w) >> 20], 1u);
    }
    __syncthreads();
    uint32_t* o = hist + ((size_t)b * NSLICE + sl) * NBINS;
    for (int i = t; i < NBINS; i += 1024) o[i] = lh[i];
}

// K2: merge slices, find bucket where cumulative-from-top crosses PRE; zero cnt
__global__ void k_findbucket(const uint32_t* __restrict__ hist, uint32_t* __restrict__ bucket,
                             uint32_t* __restrict__ cnt) {
    int b = blockIdx.x;
    int t = threadIdx.x;                          // 256 threads, 16 bins each
    if (t == 0) cnt[b * CNTSTRIDE] = 0;           // runs before k_compact (stream order)
    __shared__ uint32_t csum[256];
    __shared__ uint32_t csuf[257];
    const uint32_t* hb = hist + (size_t)b * NSLICE * NBINS;
    uint32_t binv[16];
    uint32_t s = 0;
    for (int u = 0; u < 16; ++u) {
        uint32_t v = 0;
        for (int sl = 0; sl < NSLICE; ++sl) v += hb[(size_t)sl * NBINS + t * 16 + u];
        binv[u] = v; s += v;
    }
    csum[t] = s;
    __syncthreads();
    if (t == 0) {
        uint32_t acc = 0;
        csuf[256] = 0;
        for (int c = 255; c >= 0; --c) { acc += csum[c]; csuf[c] = acc; }
    }
    __syncthreads();
    uint32_t cum = csuf[t + 1];
    for (int u = 15; u >= 0; --u) {
        uint32_t c = binv[u];
        if (cum < PRE && cum + c >= PRE) bucket[b] = (uint32_t)(t * 16 + u);
        cum += c;
    }
}

// decode + clip one proposal; store packed sort key and box at compact position.
__device__ __forceinline__ void decode_store(int rem, uint32_t key, uint32_t pos, int b,
                                             const float* __restrict__ deltas,
                                             const float* __restrict__ anchors,
                                             float limx, float limy,
                                             ull* __restrict__ pb, float4* __restrict__ bC) {
#pragma clang fp contract(off)
    int a = rem / HW;                 // anchor channel
    int pix = rem - a * HW;           // h*W + w
    uint32_t idx = (uint32_t)(pix * NA + a);
    // key desc, then ~idx desc (= idx asc); pos never decides ((key,idx) unique).
    // Real items are never 0: (~idx & 0x3FFFF) == 0 needs idx == 0x3FFFF > NITEMS.
    pb[pos] = ((ull)key << 32) | ((ull)((~idx) & 0x3FFFFu) << 13) | pos;
    int wx = pix & (WW - 1);
    int hy = pix >> 7;
    const float* D = deltas + (size_t)b * (4 * NA * HW) + (size_t)(4 * a) * HW + hy * WW + wx;
    float dx = D[0], dy = D[HW], dw = D[2 * HW], dh = D[3 * HW];
    float ax1 = anchors[4 * a + 0], ay1 = anchors[4 * a + 1];
    float ax2 = anchors[4 * a + 2], ay2 = anchors[4 * a + 3];
    float sx = (float)(wx * 16), sy = (float)(hy * 16);
    float x1 = ax1 + sx, y1 = ay1 + sy, x2 = ax2 + sx, y2 = ay2 + sy;
    float w = x2 - x1 + 1.0f;
    float h = y2 - y1 + 1.0f;
    float cx = x1 + 0.5f * w;
    float cy = y1 + 0.5f * h;
    float pcx = dx * w + cx;
    float pcy = dy * h + cy;
    float pw = (float)exp((double)dw) * w;
    float ph = (float)exp((double)dh) * h;
    float px1 = pcx - 0.5f * pw;
    float py1 = pcy - 0.5f * ph;
    float px2 = pcx + 0.5f * pw;
    float py2 = pcy + 0.5f * ph;
    px1 = fminf(fmaxf(px1, 0.0f), limx);
    py1 = fminf(fmaxf(py1, 0.0f), limy);
    px2 = fminf(fmaxf(px2, 0.0f), limx);
    py2 = fminf(fmaxf(py2, 0.0f), limy);
    bC[pos] = make_float4(px1, py1, px2, py2);
}

// K3: compact + DECODE at full parallelism (2304 blocks); one padded-line atomic per block
__global__ __launch_bounds__(256) void k_compact(const float4* __restrict__ scores4,
                                                 const uint32_t* __restrict__ bucket,
                                                 uint32_t* __restrict__ cnt,
                                                 ull* __restrict__ pairs,
                                                 float4* __restrict__ boxesC,
                                                 const float* __restrict__ deltas,
                                                 const float* __restrict__ im_info,
                                                 const float* __restrict__ anchors) {
    int b = blockIdx.x / CBLK;
    int blk = blockIdx.x % CBLK;
    int t = threadIdx.x;
    int lane = t & 63, wid = t >> 6;
    uint32_t bkt = bucket[b];
    size_t base4 = ((size_t)b * (2 * NA * HW) + (size_t)NA * HW) / 4;
    float4 f = scores4[base4 + (size_t)blk * 256 + t];
    int item0 = blk * 1024 + t * 4;
    uint32_t k0 = fkey(f.x), k1 = fkey(f.y), k2 = fkey(f.z), k3 = fkey(f.w);
    bool p0 = (k0 >> 20) >= bkt, p1 = (k1 >> 20) >= bkt;
    bool p2 = (k2 >> 20) >= bkt, p3 = (k3 >> 20) >= bkt;
    ull m0 = __ballot(p0), m1 = __ballot(p1);
    ull m2 = __ballot(p2), m3 = __ballot(p3);
    uint32_t c0 = (uint32_t)__popcll(m0), c1 = (uint32_t)__popcll(m1);
    uint32_t c2 = (uint32_t)__popcll(m2), c3 = (uint32_t)__popcll(m3);
    uint32_t wcnt = c0 + c1 + c2 + c3;
    __shared__ uint32_t swc[4];
    __shared__ uint32_t sbase;
    if (lane == 0) swc[wid] = wcnt;
    __syncthreads();
    if (t == 0) {
        uint32_t a0 = swc[0], a1 = swc[1], a2 = swc[2], a3 = swc[3];
        uint32_t tot = a0 + a1 + a2 + a3;
        sbase = tot ? atomicAdd(&cnt[b * CNTSTRIDE], tot) : 0u;
        swc[0] = 0; swc[1] = a0; swc[2] = a0 + a1; swc[3] = a0 + a1 + a2;
    }
    __syncthreads();
    uint32_t wbase = sbase + swc[wid];
    ull below = ((ull)1 << lane) - 1ull;
    ull* pb = pairs + (size_t)b * CAP;
    float4* bC = boxesC + (size_t)b * CAP;
    float limx = im_info[b * 3 + 1] - 1.0f;
    float limy = im_info[b * 3 + 0] - 1.0f;
    uint32_t pos;
    if (p0) { pos = wbase + (uint32_t)__popcll(m0 & below);
              if (pos < CAP) decode_store(item0 + 0, k0, pos, b, deltas, anchors, limx, limy, pb, bC); }
    if (p1) { pos = wbase + c0 + (uint32_t)__popcll(m1 & below);
              if (pos < CAP) decode_store(item0 + 1, k1, pos, b, deltas, anchors, limx, limy, pb, bC); }
    if (p2) { pos = wbase + c0 + c1 + (uint32_t)__popcll(m2 & below);
              if (pos < CAP) decode_store(item0 + 2, k2, pos, b, deltas, anchors, limx, limy, pb, bC); }
    if (p3) { pos = wbase + c0 + c1 + c2 + (uint32_t)__popcll(m3 & below);
              if (pos < CAP) decode_store(item0 + 3, k3, pos, b, deltas, anchors, limx, limy, pb, bC); }
}

// K4a: per-chunk bitonic sort, ALL chunks descending (k=2..2048), 64 blocks.
__global__ __launch_bounds__(1024) void k_sort1(ull* __restrict__ pairs,
                                                const uint32_t* __restrict__ cnt) {
    int b = blockIdx.x >> 2;
    int m = blockIdx.x & 3;
    int t = threadIdx.x;
    __shared__ ull lb[2][S1CH + (S1CH >> 3)];
    uint32_t n = cnt[b * CNTSTRIDE];
    if (n > CAP) n = CAP;
    ull* pb = pairs + (size_t)b * CAP;
    int base = m * S1CH;
    ull v[2];
#pragma unroll
    for (int r = 0; r < 2; ++r) {
        int e = base + 2 * t + r;
        v[r] = (e < (int)n) ? pb[e] : 0ull;
    }
    int phase = 0;
    for (int k = 2; k <= S1CH; k <<= 1) {
        bool topk = (k == S1CH);           // final stage: descending for ALL chunks
        for (int j = k >> 1; j > 0; j >>= 1) {
            if (j == 1) {
                int el = 2 * t;
                bool up = topk ? true : ((el & k) == 0);
                ull a = v[0], c = v[1];
                if ((a < c) == up) { v[0] = c; v[1] = a; }
            } else if (j <= 64) {
                int lm = j >> 1;
#pragma unroll
                for (int r = 0; r < 2; ++r) {
                    ull pv = shfl_xor_u64(v[r], lm);
                    int el = 2 * t + r;
                    bool up = topk ? true : ((el & k) == 0);
                    bool takeMax = (up == ((el & j) == 0));
                    v[r] = ce_sel(v[r], pv, takeMax);
                }
            } else {
                ull* buf = lb[phase & 1];
                ++phase;
#pragma unroll
                for (int r = 0; r < 2; ++r) { int el = 2 * t + r; buf[el + (el >> 3)] = v[r]; }
                __syncthreads();
#pragma unroll
                for (int r = 0; r < 2; ++r) {
                    int el = 2 * t + r;
                    int ep = el ^ j;
                    ull pv = buf[ep + (ep >> 3)];
                    bool up = topk ? true : ((el & k) == 0);
                    bool takeMax = (up == ((el & j) == 0));
                    v[r] = ce_sel(v[r], pv, takeMax);
                }
            }
        }
    }
#pragma unroll
    for (int r = 0; r < 2; ++r) pb[base + 2 * t + r] = v[r];
}

// K4b: merge-by-rank. 4 sorted (descending) 2048-chunks staged in LDS; final
// position = own index + 3 binary searches (count-of-strictly-greater, exact
// on unique keys; pad zeros always rank >= PRE since >= PRE real items exist).
// No merge network, 2 barriers total. Scatters pre-decoded boxes via pos field.
__global__ __launch_bounds__(1024) void k_rank2(const ull* __restrict__ pairs,
                                                const float4* __restrict__ boxesC,
                                                float4* __restrict__ boxes) {
    int b = blockIdx.x;
    int t = threadIdx.x;
    __shared__ ull s[CAP];                 // 64 KB: 4 sorted chunks
    const ull* pb = pairs + (size_t)b * CAP;
    for (int e = t; e < CAP; e += 1024) s[e] = pb[e];
    __syncthreads();
    const float4* bC = boxesC + (size_t)b * CAP;
    float4* bo = boxes + (size_t)b * PRE;
#pragma unroll
    for (int r = 0; r < 8; ++r) {
        int e = (t << 3) + r;              // element index
        ull x = s[e];
        int m = e >> 11;                   // own chunk
        uint32_t rank = (uint32_t)(e & 2047);
#pragma unroll
        for (int q = 0; q < 4; ++q) {
            if (q == m) continue;
            const ull* cq = s + (q << 11);
            int lo = 0, hi = S1CH;         // first idx with cq[idx] <= x
            while (lo < hi) {
                int mid = (lo + hi) >> 1;
                if (cq[mid] > x) lo = mid + 1; else hi = mid;
            }
            rank += (uint32_t)lo;
        }
        if (rank < PRE) bo[rank] = bC[(uint32_t)(x & 0x1FFFu)];
    }
}

// K5: precompute the 64x64 diagonal suppression matrices for ALL chunks in
// parallel (1504 blocks). Bit-identical IoU code.
__global__ __launch_bounds__(256) void k_diag(const float4* __restrict__ boxes,
                                              ull* __restrict__ smaskG) {
#pragma clang fp contract(off)
    int b = blockIdx.x / NCH;
    int ch = blockIdx.x % NCH;
    int lane = threadIdx.x & 63;
    int wv = threadIdx.x >> 6;             // 0..3
    int c0 = ch * 64;
    int c = c0 + lane;
    float4 cb = (c < PRE) ? boxes[(size_t)b * PRE + c] : make_float4(0.f, 0.f, 0.f, 0.f);
    float ca = (cb.z - cb.x + 1.0f) * (cb.w - cb.y + 1.0f);
    ull* mrow = smaskG + ((size_t)b * NCH + ch) * 64;
    for (int ii = 0; ii < 16; ++ii) {
        int i = wv * 16 + ii;
        int ci = c0 + i;
        float4 ib = (ci < PRE) ? boxes[(size_t)b * PRE + ci] : make_float4(0.f, 0.f, 0.f, 0.f);
        float ia = (ib.z - ib.x + 1.0f) * (ib.w - ib.y + 1.0f);
        float iwr = fminf(ib.z, cb.z) - fmaxf(ib.x, cb.x) + 1.0f;
        float ihr = fminf(ib.w, cb.w) - fmaxf(ib.y, cb.y) + 1.0f;
        bool sup = false;
        if (iwr > 0.0f && ihr > 0.0f) {    // exact: else iou == 0
            float inter = iwr * ihr;
            sup = (inter / ((ia + ca) - inter)) > NMS_T;
        }
        ull m = __ballot(sup);
        if (lane == 0) mrow[i] = m;
    }
}

// K6: 64-wide matrix-greedy NMS (round-15 structure). Per round: 16 waves test
// the 64 candidates vs kept list (slice 16, x4 independent-load unroll), wave 0
// preloads its mask row, B1, wave-0 PARALLEL-MIS greedy (exact lexicographic
// greedy, ~2-4 butterfly iterations), B2.
__global__ __launch_bounds__(1024) void k_nms(const float4* __restrict__ boxes,
                                              const ull* __restrict__ smaskG,
                                              float* __restrict__ out) {
#pragma clang fp contract(off)
    const int b = blockIdx.x;
    const int t = threadIdx.x;
    const int lane = t & 63;
    const int wv = t >> 6;                 // 0..15
    __shared__ float4 kbox[POST + 64];     // kept boxes, index order
    __shared__ float  karea[POST + 64];
    __shared__ ull    killm[16];
    __shared__ int    skept;
    if (t == 0) skept = 0;
    __syncthreads();
    const ull below = ((ull)1 << lane) - 1ull;
    for (int r = 0; r < NCH; ++r) {
        int kept = skept;                  // uniform (post-barrier)
        if (kept >= POST) break;
        int c0 = r * 64;
        int c = c0 + lane;
        bool valid = (c < PRE);
        float4 cb = valid ? boxes[(size_t)b * PRE + c]
                          : make_float4(0.f, 0.f, 0.f, 0.f);
        float ca = (cb.z - cb.x + 1.0f) * (cb.w - cb.y + 1.0f);
        ull rowmask = 0;
        if (wv == 0) rowmask = smaskG[((size_t)b * NCH + r) * 64 + lane];  // hidden under vs-kept
        // vs-kept: slice wv of 16, unrolled x4 with independent loads
        bool killed = false;
        for (int k = wv; k < kept; k += 64) {
            int k1 = k + 16, k2 = k + 32, k3 = k + 48;
            float4 b0 = kbox[k];
            float4 b1v, b2v, b3v;
            float a0 = karea[k], a1 = 0.f, a2 = 0.f, a3 = 0.f;
            bool h1 = k1 < kept, h2 = k2 < kept, h3 = k3 < kept;
            if (h1) { b1v = kbox[k1]; a1 = karea[k1]; }
            if (h2) { b2v = kbox[k2]; a2 = karea[k2]; }
            if (h3) { b3v = kbox[k3]; a3 = karea[k3]; }
            bool kk = false;
            {
                float iw = fminf(b0.z, cb.z) - fmaxf(b0.x, cb.x) + 1.0f;
                float ih = fminf(b0.w, cb.w) - fmaxf(b0.y, cb.y) + 1.0f;
                if (iw > 0.0f && ih > 0.0f) {
                    float inter = iw * ih;
                    kk |= (inter / ((a0 + ca) - inter)) > NMS_T;
                }
            }
            if (h1) {
                float iw = fminf(b1v.z, cb.z) - fmaxf(b1v.x, cb.x) + 1.0f;
                float ih = fminf(b1v.w, cb.w) - fmaxf(b1v.y, cb.y) + 1.0f;
                if (iw > 0.0f && ih > 0.0f) {
                    float inter = iw * ih;
                    kk |= (inter / ((a1 + ca) - inter)) > NMS_T;
                }
            }
            if (h2) {
                float iw = fminf(b2v.z, cb.z) - fmaxf(b2v.x, cb.x) + 1.0f;
                float ih = fminf(b2v.w, cb.w) - fmaxf(b2v.y, cb.y) + 1.0f;
                if (iw > 0.0f && ih > 0.0f) {
                    float inter = iw * ih;
                    kk |= (inter / ((a2 + ca) - inter)) > NMS_T;
                }
            }
            if (h3) {
                float iw = fminf(b3v.z, cb.z) - fmaxf(b3v.x, cb.x) + 1.0f;
                float ih = fminf(b3v.w, cb.w) - fmaxf(b3v.y, cb.y) + 1.0f;
                if (iw > 0.0f && ih > 0.0f) {
                    float inter = iw * ih;
                    kk |= (inter / ((a3 + ca) - inter)) > NMS_T;
                }
            }
            if (kk) { killed = true; break; }
        }
        ull km = __ballot(killed);         // unconditional -> no stale data
        if (lane == 0) killm[wv] = km;
        __syncthreads();                   // B1: kills visible
        if (wv == 0) {
            ull kill = 0;
#pragma unroll
            for (int q = 0; q < 16; ++q) kill |= killm[q];   // uniform LDS reads
            ull rem = __ballot(valid) & ~kill;
            ull rowm = rowmask & ~(1ull << lane);            // neighbors excl self
            ull keptm = 0;
            int total = kept;
            while (rem && total < POST) {  // parallel-MIS greedy (exact)
                bool alive = (rem >> lane) & 1ull;
                bool pick = alive && ((rowm & rem & below) == 0ull);
                ull pickm = __ballot(pick);
                ull contrib = pick ? rowm : 0ull;            // kept neighborhoods
                contrib |= shfl_xor_u64(contrib, 1);
                contrib |= shfl_xor_u64(contrib, 2);
                contrib |= shfl_xor_u64(contrib, 4);
                contrib |= shfl_xor_u64(contrib, 8);
                contrib |= shfl_xor_u64(contrib, 16);
                contrib |= shfl_xor_u64(contrib, 32);
                keptm |= pickm;
                total += (int)__popcll(pickm);
                rem &= ~(pickm | contrib);
            }
            int rank = (int)__popcll(keptm & below);
            if ((keptm >> lane) & 1ull) {
                kbox[kept + rank] = cb;
                karea[kept + rank] = ca;
            }
            if (lane == 0) skept = kept + (int)__popcll(keptm);
        }
        __syncthreads();                   // B2: kept list + count visible
    }
    int kf = skept < POST ? skept : POST;
    for (int k = t; k < POST; k += 1024) {
        float4 v = (k < kf) ? kbox[k] : make_float4(0.f, 0.f, 0.f, 0.f);
        float* o = out + ((size_t)b * POST + k) * 5;
        o[0] = (float)b;
        o[1] = v.x; o[2] = v.y; o[3] = v.z; o[4] = v.w;
    }
}

extern "C" void kernel_launch(void* const* d_in, const int* in_sizes, int n_in,
                              void* d_out, int out_size, void* d_ws, size_t ws_size,
                              hipStream_t stream) {
    const float* scores  = (const float*)d_in[0];
    const float* deltas  = (const float*)d_in[1];
    const float* im_info = (const float*)d_in[2];
    const float* anchors = (const float*)d_in[3];
    float* out = (float*)d_out;

    char* ws = (char*)d_ws;
    const size_t HIST_B  = (size_t)BATCH * NSLICE * NBINS * 4;   // 4 MiB
    const size_t CNT_B   = (size_t)BATCH * CNTSTRIDE * 4;        // 2 KiB (padded lines)
    const size_t BKT_B   = 64;
    const size_t PAIRS_B = (size_t)BATCH * CAP * 8;              // 1 MiB
    const size_t BOXC_B  = (size_t)BATCH * CAP * 16;             // 2 MiB
    const size_t BOX_B   = (size_t)BATCH * PRE * 16;             // 1.5 MiB
    uint32_t* hist  = (uint32_t*)ws;
    uint32_t* cnt   = (uint32_t*)(ws + HIST_B);
    uint32_t* bkt   = (uint32_t*)(ws + HIST_B + CNT_B);
    ull* pairs      = (ull*)(ws + HIST_B + CNT_B + BKT_B);
    float4* boxesC  = (float4*)(ws + HIST_B + CNT_B + BKT_B + PAIRS_B);
    float4* boxes   = (float4*)(ws + HIST_B + CNT_B + BKT_B + PAIRS_B + BOXC_B);
    ull* smaskG     = (ull*)(ws + HIST_B + CNT_B + BKT_B + PAIRS_B + BOXC_B + BOX_B);

    k_hist<<<BATCH * NSLICE, 1024, 0, stream>>>((const float4*)scores, hist);
    k_findbucket<<<BATCH, 256, 0, stream>>>(hist, bkt, cnt);
    k_compact<<<BATCH * CBLK, 256, 0, stream>>>((const float4*)scores, bkt, cnt, pairs,
                                                boxesC, deltas, im_info, anchors);
    k_sort1<<<BATCH * 4, 1024, 0, stream>>>(pairs, cnt);
    k_rank2<<<BATCH, 1024, 0, stream>>>(pairs, boxesC, boxes);
    k_diag<<<BATCH * NCH, 256, 0, stream>>>(boxes, smaskG);
    k_nms<<<BATCH, 1024, 0, stream>>>(boxes, smaskG, out);
}

// Round 20
// 107.112 us; speedup vs baseline: 2.1975x; 1.0021x over previous
//
#include <hip/hip_runtime.h>
#include <stdint.h>

typedef unsigned long long ull;

#define BATCH 16
#define NA 9
#define HH 128
#define WW 128
#define HW (HH*WW)            // 16384
#define NITEMS (NA*HW)        // 147456 per batch
#define PRE 6000
#define POST 300
#define NMS_T 0.7f
#define NBINS 4096            // top-12 bits of sortable key
#define NSLICE 16             // histogram slices per batch
#define CAP 8192
#define CBLK 144              // compact blocks per batch (1024 items each)
#define S1CH 2048             // per-block chunk for sort stage 1
#define NCH ((PRE + 63) / 64) // 94 NMS candidate chunks (64-wide)
#define CNTSTRIDE 32          // one 128B line per batch counter (atomic contention fix)

__device__ __forceinline__ uint32_t fkey(float f) {
    uint32_t u = __float_as_uint(f);
    return u ^ ((u & 0x80000000u) ? 0xFFFFFFFFu : 0x80000000u);
}

__device__ __forceinline__ ull shfl_xor_u64(ull x, int m) {
    uint32_t lo = (uint32_t)x, hi = (uint32_t)(x >> 32);
    lo = (uint32_t)__shfl_xor((int)lo, m, 64);
    hi = (uint32_t)__shfl_xor((int)hi, m, 64);
    return ((ull)hi << 32) | lo;
}

__device__ __forceinline__ ull ce_sel(ull a, ull b, bool takeMax) {
    return takeMax ? (a >= b ? a : b) : (a <= b ? a : b);
}

// K1: per-(batch,slice) histogram of top-12 key bits; 4-way LDS sub-histograms
// (wave&3) cut same-hot-bin atomic serialization ~4x; non-atomic global write.
__global__ __launch_bounds__(1024) void k_hist(const float4* __restrict__ scores4,
                                               uint32_t* __restrict__ hist) {
    int b = blockIdx.x / NSLICE;
    int sl = blockIdx.x % NSLICE;
    int t = threadIdx.x;
    int sub = (t >> 6) & 3;
    __shared__ uint32_t lh[4][NBINS];             // 64 KB
    for (int i = t; i < 4 * NBINS; i += 1024) ((uint32_t*)lh)[i] = 0;
    __syncthreads();
    size_t base4 = ((size_t)b * (2 * NA * HW) + (size_t)NA * HW) / 4;
    const int PER = NITEMS / NSLICE / 4;          // 2304 float4 per slice
    size_t s4 = base4 + (size_t)sl * PER;
    for (int v = t; v < PER; v += 1024) {
        float4 f = scores4[s4 + v];
        atomicAdd(&lh[sub][fkey(f.x) >> 20], 1u);
        atomicAdd(&lh[sub][fkey(f.y) >> 20], 1u);
        atomicAdd(&lh[sub][fkey(f.z) >> 20], 1u);
        atomicAdd(&lh[sub][fkey(f.w) >> 20], 1u);
    }
    __syncthreads();
    uint32_t* o = hist + ((size_t)b * NSLICE + sl) * NBINS;
    for (int i = t; i < NBINS; i += 1024)
        o[i] = lh[0][i] + lh[1][i] + lh[2][i] + lh[3][i];
}

// K2: merge slices, find bucket where cumulative-from-top crosses PRE; zero cnt
__global__ void k_findbucket(const uint32_t* __restrict__ hist, uint32_t* __restrict__ bucket,
                             uint32_t* __restrict__ cnt) {
    int b = blockIdx.x;
    int t = threadIdx.x;                          // 256 threads, 16 bins each
    if (t == 0) cnt[b * CNTSTRIDE] = 0;           // runs before k_compact (stream order)
    __shared__ uint32_t csum[256];
    __shared__ uint32_t csuf[257];
    const uint32_t* hb = hist + (size_t)b * NSLICE * NBINS;
    uint32_t binv[16];
    uint32_t s = 0;
    for (int u = 0; u < 16; ++u) {
        uint32_t v = 0;
        for (int sl = 0; sl < NSLICE; ++sl) v += hb[(size_t)sl * NBINS + t * 16 + u];
        binv[u] = v; s += v;
    }
    csum[t] = s;
    __syncthreads();
    if (t == 0) {
        uint32_t acc = 0;
        csuf[256] = 0;
        for (int c = 255; c >= 0; --c) { acc += csum[c]; csuf[c] = acc; }
    }
    __syncthreads();
    uint32_t cum = csuf[t + 1];
    for (int u = 15; u >= 0; --u) {
        uint32_t c = binv[u];
        if (cum < PRE && cum + c >= PRE) bucket[b] = (uint32_t)(t * 16 + u);
        cum += c;
    }
}

// decode + clip one proposal; store packed sort key and box at compact position.
__device__ __forceinline__ void decode_store(int rem, uint32_t key, uint32_t pos, int b,
                                             const float* __restrict__ deltas,
                                             const float* __restrict__ anchors,
                                             float limx, float limy,
                                             ull* __restrict__ pb, float4* __restrict__ bC) {
#pragma clang fp contract(off)
    int a = rem / HW;                 // anchor channel
    int pix = rem - a * HW;           // h*W + w
    uint32_t idx = (uint32_t)(pix * NA + a);
    // key desc, then ~idx desc (= idx asc); pos never decides ((key,idx) unique).
    pb[pos] = ((ull)key << 32) | ((ull)((~idx) & 0x3FFFFu) << 13) | pos;
    int wx = pix & (WW - 1);
    int hy = pix >> 7;
    const float* D = deltas + (size_t)b * (4 * NA * HW) + (size_t)(4 * a) * HW + hy * WW + wx;
    float dx = D[0], dy = D[HW], dw = D[2 * HW], dh = D[3 * HW];
    float ax1 = anchors[4 * a + 0], ay1 = anchors[4 * a + 1];
    float ax2 = anchors[4 * a + 2], ay2 = anchors[4 * a + 3];
    float sx = (float)(wx * 16), sy = (float)(hy * 16);
    float x1 = ax1 + sx, y1 = ay1 + sy, x2 = ax2 + sx, y2 = ay2 + sy;
    float w = x2 - x1 + 1.0f;
    float h = y2 - y1 + 1.0f;
    float cx = x1 + 0.5f * w;
    float cy = y1 + 0.5f * h;
    float pcx = dx * w + cx;
    float pcy = dy * h + cy;
    float pw = (float)exp((double)dw) * w;
    float ph = (float)exp((double)dh) * h;
    float px1 = pcx - 0.5f * pw;
    float py1 = pcy - 0.5f * ph;
    float px2 = pcx + 0.5f * pw;
    float py2 = pcy + 0.5f * ph;
    px1 = fminf(fmaxf(px1, 0.0f), limx);
    py1 = fminf(fmaxf(py1, 0.0f), limy);
    px2 = fminf(fmaxf(px2, 0.0f), limx);
    py2 = fminf(fmaxf(py2, 0.0f), limy);
    bC[pos] = make_float4(px1, py1, px2, py2);
}

// K3: compact + DECODE at full parallelism (2304 blocks); one padded-line atomic per block
__global__ __launch_bounds__(256) void k_compact(const float4* __restrict__ scores4,
                                                 const uint32_t* __restrict__ bucket,
                                                 uint32_t* __restrict__ cnt,
                                                 ull* __restrict__ pairs,
                                                 float4* __restrict__ boxesC,
                                                 const float* __restrict__ deltas,
                                                 const float* __restrict__ im_info,
                                                 const float* __restrict__ anchors) {
    int b = blockIdx.x / CBLK;
    int blk = blockIdx.x % CBLK;
    int t = threadIdx.x;
    int lane = t & 63, wid = t >> 6;
    uint32_t bkt = bucket[b];
    size_t base4 = ((size_t)b * (2 * NA * HW) + (size_t)NA * HW) / 4;
    float4 f = scores4[base4 + (size_t)blk * 256 + t];
    int item0 = blk * 1024 + t * 4;
    uint32_t k0 = fkey(f.x), k1 = fkey(f.y), k2 = fkey(f.z), k3 = fkey(f.w);
    bool p0 = (k0 >> 20) >= bkt, p1 = (k1 >> 20) >= bkt;
    bool p2 = (k2 >> 20) >= bkt, p3 = (k3 >> 20) >= bkt;
    ull m0 = __ballot(p0), m1 = __ballot(p1);
    ull m2 = __ballot(p2), m3 = __ballot(p3);
    uint32_t c0 = (uint32_t)__popcll(m0), c1 = (uint32_t)__popcll(m1);
    uint32_t c2 = (uint32_t)__popcll(m2), c3 = (uint32_t)__popcll(m3);
    uint32_t wcnt = c0 + c1 + c2 + c3;
    __shared__ uint32_t swc[4];
    __shared__ uint32_t sbase;
    if (lane == 0) swc[wid] = wcnt;
    __syncthreads();
    if (t == 0) {
        uint32_t a0 = swc[0], a1 = swc[1], a2 = swc[2], a3 = swc[3];
        uint32_t tot = a0 + a1 + a2 + a3;
        sbase = tot ? atomicAdd(&cnt[b * CNTSTRIDE], tot) : 0u;
        swc[0] = 0; swc[1] = a0; swc[2] = a0 + a1; swc[3] = a0 + a1 + a2;
    }
    __syncthreads();
    uint32_t wbase = sbase + swc[wid];
    ull below = ((ull)1 << lane) - 1ull;
    ull* pb = pairs + (size_t)b * CAP;
    float4* bC = boxesC + (size_t)b * CAP;
    float limx = im_info[b * 3 + 1] - 1.0f;
    float limy = im_info[b * 3 + 0] - 1.0f;
    uint32_t pos;
    if (p0) { pos = wbase + (uint32_t)__popcll(m0 & below);
              if (pos < CAP) decode_store(item0 + 0, k0, pos, b, deltas, anchors, limx, limy, pb, bC); }
    if (p1) { pos = wbase + c0 + (uint32_t)__popcll(m1 & below);
              if (pos < CAP) decode_store(item0 + 1, k1, pos, b, deltas, anchors, limx, limy, pb, bC); }
    if (p2) { pos = wbase + c0 + c1 + (uint32_t)__popcll(m2 & below);
              if (pos < CAP) decode_store(item0 + 2, k2, pos, b, deltas, anchors, limx, limy, pb, bC); }
    if (p3) { pos = wbase + c0 + c1 + c2 + (uint32_t)__popcll(m3 & below);
              if (pos < CAP) decode_store(item0 + 3, k3, pos, b, deltas, anchors, limx, limy, pb, bC); }
}

// K4a: per-chunk bitonic sort, ALL chunks descending (k=2..2048), 64 blocks.
__global__ __launch_bounds__(1024) void k_sort1(ull* __restrict__ pairs,
                                                const uint32_t* __restrict__ cnt) {
    int b = blockIdx.x >> 2;
    int m = blockIdx.x & 3;
    int t = threadIdx.x;
    __shared__ ull lb[2][S1CH + (S1CH >> 3)];
    uint32_t n = cnt[b * CNTSTRIDE];
    if (n > CAP) n = CAP;
    ull* pb = pairs + (size_t)b * CAP;
    int base = m * S1CH;
    ull v[2];
#pragma unroll
    for (int r = 0; r < 2; ++r) {
        int e = base + 2 * t + r;
        v[r] = (e < (int)n) ? pb[e] : 0ull;
    }
    int phase = 0;
    for (int k = 2; k <= S1CH; k <<= 1) {
        bool topk = (k == S1CH);           // final stage: descending for ALL chunks
        for (int j = k >> 1; j > 0; j >>= 1) {
            if (j == 1) {
                int el = 2 * t;
                bool up = topk ? true : ((el & k) == 0);
                ull a = v[0], c = v[1];
                if ((a < c) == up) { v[0] = c; v[1] = a; }
            } else if (j <= 64) {
                int lm = j >> 1;
#pragma unroll
                for (int r = 0; r < 2; ++r) {
                    ull pv = shfl_xor_u64(v[r], lm);
                    int el = 2 * t + r;
                    bool up = topk ? true : ((el & k) == 0);
                    bool takeMax = (up == ((el & j) == 0));
                    v[r] = ce_sel(v[r], pv, takeMax);
                }
            } else {
                ull* buf = lb[phase & 1];
                ++phase;
#pragma unroll
                for (int r = 0; r < 2; ++r) { int el = 2 * t + r; buf[el + (el >> 3)] = v[r]; }
                __syncthreads();
#pragma unroll
                for (int r = 0; r < 2; ++r) {
                    int el = 2 * t + r;
                    int ep = el ^ j;
                    ull pv = buf[ep + (ep >> 3)];
                    bool up = topk ? true : ((el & k) == 0);
                    bool takeMax = (up == ((el & j) == 0));
                    v[r] = ce_sel(v[r], pv, takeMax);
                }
            }
        }
    }
#pragma unroll
    for (int r = 0; r < 2; ++r) pb[base + 2 * t + r] = v[r];
}

// K4b: merge-by-rank. 4 sorted (descending) 2048-chunks staged in LDS; final
// position = own index + 3 binary searches (count-of-strictly-greater, exact
// on unique keys; pad zeros always rank >= PRE since >= PRE real items exist).
__global__ __launch_bounds__(1024) void k_rank2(const ull* __restrict__ pairs,
                                                const float4* __restrict__ boxesC,
                                                float4* __restrict__ boxes) {
    int b = blockIdx.x;
    int t = threadIdx.x;
    __shared__ ull s[CAP];                 // 64 KB: 4 sorted chunks
    const ull* pb = pairs + (size_t)b * CAP;
    for (int e = t; e < CAP; e += 1024) s[e] = pb[e];
    __syncthreads();
    const float4* bC = boxesC + (size_t)b * CAP;
    float4* bo = boxes + (size_t)b * PRE;
#pragma unroll
    for (int r = 0; r < 8; ++r) {
        int e = (t << 3) + r;              // element index
        ull x = s[e];
        int m = e >> 11;                   // own chunk
        uint32_t rank = (uint32_t)(e & 2047);
#pragma unroll
        for (int q = 0; q < 4; ++q) {
            if (q == m) continue;
            const ull* cq = s + (q << 11);
            int lo = 0, hi = S1CH;         // first idx with cq[idx] <= x
            while (lo < hi) {
                int mid = (lo + hi) >> 1;
                if (cq[mid] > x) lo = mid + 1; else hi = mid;
            }
            rank += (uint32_t)lo;
        }
        if (rank < PRE) bo[rank] = bC[(uint32_t)(x & 0x1FFFu)];
    }
}

// K5: precompute the 64x64 diagonal suppression matrices for ALL chunks in
// parallel (1504 blocks). Bit-identical IoU code.
__global__ __launch_bounds__(256) void k_diag(const float4* __restrict__ boxes,
                                              ull* __restrict__ smaskG) {
#pragma clang fp contract(off)
    int b = blockIdx.x / NCH;
    int ch = blockIdx.x % NCH;
    int lane = threadIdx.x & 63;
    int wv = threadIdx.x >> 6;             // 0..3
    int c0 = ch * 64;
    int c = c0 + lane;
    float4 cb = (c < PRE) ? boxes[(size_t)b * PRE + c] : make_float4(0.f, 0.f, 0.f, 0.f);
    float ca = (cb.z - cb.x + 1.0f) * (cb.w - cb.y + 1.0f);
    ull* mrow = smaskG + ((size_t)b * NCH + ch) * 64;
    for (int ii = 0; ii < 16; ++ii) {
        int i = wv * 16 + ii;
        int ci = c0 + i;
        float4 ib = (ci < PRE) ? boxes[(size_t)b * PRE + ci] : make_float4(0.f, 0.f, 0.f, 0.f);
        float ia = (ib.z - ib.x + 1.0f) * (ib.w - ib.y + 1.0f);
        float iwr = fminf(ib.z, cb.z) - fmaxf(ib.x, cb.x) + 1.0f;
        float ihr = fminf(ib.w, cb.w) - fmaxf(ib.y, cb.y) + 1.0f;
        bool sup = false;
        if (iwr > 0.0f && ihr > 0.0f) {    // exact: else iou == 0
            float inter = iwr * ihr;
            sup = (inter / ((ia + ca) - inter)) > NMS_T;
        }
        ull m = __ballot(sup);
        if (lane == 0) mrow[i] = m;
    }
}

// K6: 64-wide matrix-greedy NMS (round-15 structure) + next-round software
// prefetch of candidate box and mask row (pulls ~200cy L2 latency off the
// per-round critical path). Wave-0 PARALLEL-MIS greedy (exact lexicographic).
__global__ __launch_bounds__(1024) void k_nms(const float4* __restrict__ boxes,
                                              const ull* __restrict__ smaskG,
                                              float* __restrict__ out) {
#pragma clang fp contract(off)
    const int b = blockIdx.x;
    const int t = threadIdx.x;
    const int lane = t & 63;
    const int wv = t >> 6;                 // 0..15
    __shared__ float4 kbox[POST + 64];     // kept boxes, index order
    __shared__ float  karea[POST + 64];
    __shared__ ull    killm[16];
    __shared__ int    skept;
    if (t == 0) skept = 0;
    __syncthreads();
    const ull below = ((ull)1 << lane) - 1ull;
    const float4* bb = boxes + (size_t)b * PRE;
    const ull* mb = smaskG + (size_t)b * NCH * 64;
    const float4 zf = make_float4(0.f, 0.f, 0.f, 0.f);
    // prologue: prefetch round 0
    float4 cb_n = (lane < PRE) ? bb[lane] : zf;    // c0=0, always valid
    ull rowmask_n = (wv == 0) ? mb[lane] : 0;
    for (int r = 0; r < NCH; ++r) {
        int kept = skept;                  // uniform (post-barrier)
        if (kept >= POST) break;
        int c0 = r * 64;
        int c = c0 + lane;
        bool valid = (c < PRE);
        float4 cb = cb_n;
        ull rowmask = rowmask_n;
        // issue next round's prefetch (completes during the scan)
        if (r + 1 < NCH) {
            int c2 = (r + 1) * 64 + lane;
            cb_n = (c2 < PRE) ? bb[c2] : zf;
            if (wv == 0) rowmask_n = mb[(size_t)(r + 1) * 64 + lane];
        }
        float ca = (cb.z - cb.x + 1.0f) * (cb.w - cb.y + 1.0f);
        // vs-kept: slice wv of 16, unrolled x4 with independent loads
        bool killed = false;
        for (int k = wv; k < kept; k += 64) {
            int k1 = k + 16, k2 = k + 32, k3 = k + 48;
            float4 b0 = kbox[k];
            float4 b1v, b2v, b3v;
            float a0 = karea[k], a1 = 0.f, a2 = 0.f, a3 = 0.f;
            bool h1 = k1 < kept, h2 = k2 < kept, h3 = k3 < kept;
            if (h1) { b1v = kbox[k1]; a1 = karea[k1]; }
            if (h2) { b2v = kbox[k2]; a2 = karea[k2]; }
            if (h3) { b3v = kbox[k3]; a3 = karea[k3]; }
            bool kk = false;
            {
                float iw = fminf(b0.z, cb.z) - fmaxf(b0.x, cb.x) + 1.0f;
                float ih = fminf(b0.w, cb.w) - fmaxf(b0.y, cb.y) + 1.0f;
                if (iw > 0.0f && ih > 0.0f) {
                    float inter = iw * ih;
                    kk |= (inter / ((a0 + ca) - inter)) > NMS_T;
                }
            }
            if (h1) {
                float iw = fminf(b1v.z, cb.z) - fmaxf(b1v.x, cb.x) + 1.0f;
                float ih = fminf(b1v.w, cb.w) - fmaxf(b1v.y, cb.y) + 1.0f;
                if (iw > 0.0f && ih > 0.0f) {
                    float inter = iw * ih;
                    kk |= (inter / ((a1 + ca) - inter)) > NMS_T;
                }
            }
            if (h2) {
                float iw = fminf(b2v.z, cb.z) - fmaxf(b2v.x, cb.x) + 1.0f;
                float ih = fminf(b2v.w, cb.w) - fmaxf(b2v.y, cb.y) + 1.0f;
                if (iw > 0.0f && ih > 0.0f) {
                    float inter = iw * ih;
                    kk |= (inter / ((a2 + ca) - inter)) > NMS_T;
                }
            }
            if (h3) {
                float iw = fminf(b3v.z, cb.z) - fmaxf(b3v.x, cb.x) + 1.0f;
                float ih = fminf(b3v.w, cb.w) - fmaxf(b3v.y, cb.y) + 1.0f;
                if (iw > 0.0f && ih > 0.0f) {
                    float inter = iw * ih;
                    kk |= (inter / ((a3 + ca) - inter)) > NMS_T;
                }
            }
            if (kk) { killed = true; break; }
        }
        ull km = __ballot(killed);         // unconditional -> no stale data
        if (lane == 0) killm[wv] = km;
        __syncthreads();                   // B1: kills visible
        if (wv == 0) {
            ull kill = 0;
#pragma unroll
            for (int q = 0; q < 16; ++q) kill |= killm[q];   // uniform LDS reads
            ull rem = __ballot(valid) & ~kill;
            ull rowm = rowmask & ~(1ull << lane);            // neighbors excl self
            ull keptm = 0;
            int total = kept;
            while (rem && total < POST) {  // parallel-MIS greedy (exact)
                bool alive = (rem >> lane) & 1ull;
                bool pick = alive && ((rowm & rem & below) == 0ull);
                ull pickm = __ballot(pick);
                ull contrib = pick ? rowm : 0ull;            // kept neighborhoods
                contrib |= shfl_xor_u64(contrib, 1);
                contrib |= shfl_xor_u64(contrib, 2);
                contrib |= shfl_xor_u64(contrib, 4);
                contrib |= shfl_xor_u64(contrib, 8);
                contrib |= shfl_xor_u64(contrib, 16);
                contrib |= shfl_xor_u64(contrib, 32);
                keptm |= pickm;
                total += (int)__popcll(pickm);
                rem &= ~(pickm | contrib);
            }
            int rank = (int)__popcll(keptm & below);
            if ((keptm >> lane) & 1ull) {
                kbox[kept + rank] = cb;
                karea[kept + rank] = ca;
            }
            if (lane == 0) skept = kept + (int)__popcll(keptm);
        }
        __syncthreads();                   // B2: kept list + count visible
    }
    int kf = skept < POST ? skept : POST;
    for (int k = t; k < POST; k += 1024) {
        float4 v = (k < kf) ? kbox[k] : make_float4(0.f, 0.f, 0.f, 0.f);
        float* o = out + ((size_t)b * POST + k) * 5;
        o[0] = (float)b;
        o[1] = v.x; o[2] = v.y; o[3] = v.z; o[4] = v.w;
    }
}

extern "C" void kernel_launch(void* const* d_in, const int* in_sizes, int n_in,
                              void* d_out, int out_size, void* d_ws, size_t ws_size,
                              hipStream_t stream) {
    const float* scores  = (const float*)d_in[0];
    const float* deltas  = (const float*)d_in[1];
    const float* im_info = (const float*)d_in[2];
    const float* anchors = (const float*)d_in[3];
    float* out = (float*)d_out;

    char* ws = (char*)d_ws;
    const size_t HIST_B  = (size_t)BATCH * NSLICE * NBINS * 4;   // 4 MiB
    const size_t CNT_B   = (size_t)BATCH * CNTSTRIDE * 4;        // 2 KiB (padded lines)
    const size_t BKT_B   = 64;
    const size_t PAIRS_B = (size_t)BATCH * CAP * 8;              // 1 MiB
    const size_t BOXC_B  = (size_t)BATCH * CAP * 16;             // 2 MiB
    const size_t BOX_B   = (size_t)BATCH * PRE * 16;             // 1.5 MiB
    uint32_t* hist  = (uint32_t*)ws;
    uint32_t* cnt   = (uint32_t*)(ws + HIST_B);
    uint32_t* bkt   = (uint32_t*)(ws + HIST_B + CNT_B);
    ull* pairs      = (ull*)(ws + HIST_B + CNT_B + BKT_B);
    float4* boxesC  = (float4*)(ws + HIST_B + CNT_B + BKT_B + PAIRS_B);
    float4* boxes   = (float4*)(ws + HIST_B + CNT_B + BKT_B + PAIRS_B + BOXC_B);
    ull* smaskG     = (ull*)(ws + HIST_B + CNT_B + BKT_B + PAIRS_B + BOXC_B + BOX_B);

    k_hist<<<BATCH * NSLICE, 1024, 0, stream>>>((const float4*)scores, hist);
    k_findbucket<<<BATCH, 256, 0, stream>>>(hist, bkt, cnt);
    k_compact<<<BATCH * CBLK, 256, 0, stream>>>((const float4*)scores, bkt, cnt, pairs,
                                                boxesC, deltas, im_info, anchors);
    k_sort1<<<BATCH * 4, 1024, 0, stream>>>(pairs, cnt);
    k_rank2<<<BATCH, 1024, 0, stream>>>(pairs, boxesC, boxes);
    k_diag<<<BATCH * NCH, 256, 0, stream>>>(boxes, smaskG);
    k_nms<<<BATCH, 1024, 0, stream>>>(boxes, smaskG, out);
}